// Round 3
// baseline (2602.590 us; speedup 1.0000x reference)
//
#include <hip/hip_runtime.h>

#define DIMV 1024
#define SSZ 512
#define MSZ 4096
#define KPROM 128
#define NTILE 528   // 128x128 tiles over lower triangle incl diagonal: 32*33/2
#define NBLK 768    // 3 blocks/CU * 256 CUs — co-resident under launch_bounds(256,3)

typedef __attribute__((ext_vector_type(4))) float f32x4;
typedef __attribute__((ext_vector_type(4))) unsigned int u32x4;
typedef __attribute__((ext_vector_type(4))) unsigned short u16x4;
typedef __attribute__((ext_vector_type(8))) __bf16 bf16x8;

// ---------------- output layout (float element offsets) ----------------
#define OUT_M 524288ull
#define OUT_L 4718592ull
#define OUT_MU 13107200ull
#define OUT_LU 13111296ull
#define OUT_SPTR 13119488ull

// ---- scratch inside out_l region (8,388,608 floats; erased by final phase) ----
#define SC_BF16 0ull
#define SC_NORMS 2100000ull
#define SC_TOPIDX 2117000ull
#define SC_LPART 2120000ull
#define SC_RV 2260000ull
#define SC_LMEAN 2262000ull
#define SC_Q 2264000ull
#define SC_LOGITS 2413000ull
#define SC_BEST 2414000ull
#define SC_MNORM 2415000ull
#define SC_SIMS 2420000ull
#define SC_PPV 2425000ull
#define SC_PPI 2427000ull

// ---- d_ws int layout: [0..5] ctl (lj,mi,branch,i1,i2,best); [8..11] barriers; [12..19] flags
#define F_TOPK 12
#define F_LMEAN 13
#define F_Q 14
#define F_RV 15
#define F_WS 16
#define F_BEST 17
#define F_SIMS 18
#define F_PAIR 19

__device__ __forceinline__ float wave_sum(float v) {
#pragma unroll
  for (int o = 32; o > 0; o >>= 1) v += __shfl_down(v, o, 64);
  return v;
}
__device__ __forceinline__ void wave_maxidx(float& v, int& i) {
#pragma unroll
  for (int o = 32; o > 0; o >>= 1) {
    float ov = __shfl_down(v, o, 64);
    int oi = __shfl_down(i, o, 64);
    if (ov > v || (ov == v && oi < i)) { v = ov; i = oi; }
  }
}
__device__ __forceinline__ void wave_minidx(float& v, int& i) {
#pragma unroll
  for (int o = 32; o > 0; o >>= 1) {
    float ov = __shfl_down(v, o, 64);
    int oi = __shfl_down(i, o, 64);
    if (ov < v || (ov == v && oi < i)) { v = ov; i = oi; }
  }
}
__device__ __forceinline__ unsigned short f2bf(float x) {  // RNE float->bf16
  unsigned u = __float_as_uint(x);
  return (unsigned short)((u + 0x7FFFu + ((u >> 16) & 1u)) >> 16);
}

// ---- cross-block sync primitives (device-scope; threadfence emits the L2 wb needed cross-XCD) ----
__device__ __forceinline__ void flag_set(int* f) {
  __syncthreads();
  if (threadIdx.x == 0) { __threadfence(); atomicAdd(f, 1); }
}
__device__ __forceinline__ void flag_wait(int* f, int target) {
  if (threadIdx.x == 0) {
    while (__hip_atomic_load(f, __ATOMIC_ACQUIRE, __HIP_MEMORY_SCOPE_AGENT) < target)
      __builtin_amdgcn_s_sleep(8);
  }
  __syncthreads();
}
__device__ __forceinline__ void gridbar(int* cnt, int* rel) {
  __syncthreads();
  if (threadIdx.x == 0) {
    __threadfence();
    if (__hip_atomic_fetch_add(cnt, 1, __ATOMIC_ACQ_REL, __HIP_MEMORY_SCOPE_AGENT) == NBLK - 1) {
      __hip_atomic_store(rel, 1, __ATOMIC_RELEASE, __HIP_MEMORY_SCOPE_AGENT);
    } else {
      while (__hip_atomic_load(rel, __ATOMIC_ACQUIRE, __HIP_MEMORY_SCOPE_AGENT) == 0)
        __builtin_amdgcn_s_sleep(8);
    }
  }
  __syncthreads();
}

__global__ __launch_bounds__(256, 3) void kMega(
    const float* __restrict__ cand, const float* __restrict__ s_memory,
    const float* __restrict__ m, const float* __restrict__ l_memory,
    const float* __restrict__ mu, const float* __restrict__ lu,
    const float* __restrict__ wq, const float* __restrict__ bq,
    const float* __restrict__ wk, const int* __restrict__ s_ptr,
    float* __restrict__ out, int* __restrict__ wsb) {
  __shared__ __align__(16) unsigned short At[128 * 72];  // pairmax A tile (topk overlays here)
  __shared__ __align__(16) unsigned short Bt[128 * 72];  // pairmax B tile
  __shared__ float swv[16];
  __shared__ int swi[16];
  __shared__ float ssum[16];
  __shared__ int szf[16];
  __shared__ float s_f[8];
  __shared__ int s_i[8];

  const int bid = blockIdx.x, t = threadIdx.x, lane = t & 63, w = t >> 6;

  float* out_s = out;
  float* out_m = out + OUT_M;
  float* out_l = out + OUT_L;
  float* out_mu = out + OUT_MU;
  float* out_lu = out + OUT_LU;
  float* out_sptr = out + OUT_SPTR;
  float* lsc = out_l;
  unsigned short* mb = (unsigned short*)(lsc + SC_BF16);
  float* norms = lsc + SC_NORMS;
  int* topidx = (int*)(lsc + SC_TOPIDX);
  float* lpart = lsc + SC_LPART;
  float* rv = lsc + SC_RV;
  float* lmean = lsc + SC_LMEAN;
  float* qv = lsc + SC_Q;
  float* logits = lsc + SC_LOGITS;
  int* bestp = (int*)(lsc + SC_BEST);
  float* cnormp = lsc + SC_BEST + 1;
  float* mnorm = lsc + SC_MNORM;
  float* sims = lsc + SC_SIMS;
  float* pv = lsc + SC_PPV;
  int* pidx = (int*)(lsc + SC_PPI);

  // ================= P0: norms + lpart + bf16 M + mnorm (all blocks) =================
  for (int u = bid; u < 5248; u += NBLK) {
    if (u < 4096) {  // candidate row norms, 4 rows/unit
      int row = u * 4 + w;
      const f32x4* p = (const f32x4*)(cand + (size_t)row * DIMV);
      float s = 0.f;
#pragma unroll
      for (int c = 0; c < 4; ++c) {
        f32x4 v = p[c * 64 + lane];
        s += v.x * v.x + v.y * v.y + v.z * v.z + v.w * v.w;
      }
      s = wave_sum(s);
      if (lane == 0) norms[row] = sqrtf(s);
    } else if (u < 4224) {  // l column partial sums, 64 rows/unit
      int bb = u - 4096;
      f32x4 a = {0.f, 0.f, 0.f, 0.f};
      const f32x4* base = (const f32x4*)(l_memory + (size_t)bb * 64 * DIMV);
      for (int r = 0; r < 64; ++r) a += base[r * 256 + t];
      ((f32x4*)(lpart + (size_t)bb * DIMV))[t] = a;
    } else {  // m -> bf16 + row norms, 4 rows/unit
      int row = (u - 4224) * 4 + w;
      const f32x4* mp = (const f32x4*)(m + (size_t)row * DIMV);
      float ss = 0.f;
#pragma unroll
      for (int c = 0; c < 4; ++c) {
        int i = c * 64 + lane;
        f32x4 v = mp[i];
        ss += v.x * v.x + v.y * v.y + v.z * v.z + v.w * v.w;
        u16x4 h;
        h.x = f2bf(v.x); h.y = f2bf(v.y); h.z = f2bf(v.z); h.w = f2bf(v.w);
        ((u16x4*)(mb + (size_t)row * DIMV))[i] = h;
      }
      ss = wave_sum(ss);
      if (lane == 0) mnorm[row] = sqrtf(ss);
    }
  }
  if (bid == 592) {  // zero rv accumulator with agent-scope stores (cross-XCD safe)
    for (int i = t; i < DIMV; i += 256)
      __hip_atomic_store(rv + i, 0.0f, __ATOMIC_RELAXED, __HIP_MEMORY_SCOPE_AGENT);
  }
  gridbar(wsb + 8, wsb + 9);

  // ================= overlapped region: serial chain (blocks 0..59) + pairmax (64..591) ====
  if (bid == 0) {
    // ---- exact stable top-128 via 8-bit radix select (reloads norms per pass; L2-hot) ----
    int* hist = (int*)At;
    int* sh = (int*)At + 256;
    unsigned* selkey = (unsigned*)Bt;
    int* selidx = (int*)Bt + 128;
    unsigned prefix = 0, himask = 0;
    int remaining = KPROM;
    for (int p = 24; p >= 0; p -= 8) {
      hist[t] = 0;
      __syncthreads();
      for (int j = 0; j < 64; ++j) {
        unsigned k = __float_as_uint(norms[t * 64 + j]);  // norms>0: bit order == value order
        if ((k & himask) == prefix) atomicAdd(&hist[(k >> p) & 255], 1);
      }
      __syncthreads();
      sh[t] = hist[t];
      __syncthreads();
      for (int o = 1; o < 256; o <<= 1) {  // suffix-inclusive: sh[d] = #keys with digit >= d
        int x = (t + o < 256) ? sh[t + o] : 0;
        __syncthreads();
        sh[t] += x;
        __syncthreads();
      }
      {
        int sfex = (t < 255) ? sh[t + 1] : 0;
        if (sfex < remaining && remaining <= sh[t]) { s_i[0] = t; s_i[1] = sfex; }
      }
      __syncthreads();
      prefix |= ((unsigned)s_i[0]) << p;
      remaining -= s_i[1];
      himask |= (0xFFu << p);
      __syncthreads();
    }
    unsigned T = prefix;  // exact 128th-largest key
    int cgt = 0, ceq = 0;
    for (int j = 0; j < 64; ++j) {
      unsigned k = __float_as_uint(norms[t * 64 + j]);
      cgt += (k > T);
      ceq += (k == T);
    }
    sh[t] = cgt;
    __syncthreads();
    for (int o = 1; o < 256; o <<= 1) {
      int x = (t >= o) ? sh[t - o] : 0;
      __syncthreads();
      sh[t] += x;
      __syncthreads();
    }
    int sgt = sh[t] - cgt, total_gt = sh[255];
    __syncthreads();
    sh[t] = ceq;
    __syncthreads();
    for (int o = 1; o < 256; o <<= 1) {
      int x = (t >= o) ? sh[t - o] : 0;
      __syncthreads();
      sh[t] += x;
      __syncthreads();
    }
    int seq = sh[t] - ceq;
    __syncthreads();
    int need_eq = KPROM - total_gt;
    int g = sgt, e = seq;
    for (int j = 0; j < 64; ++j) {
      unsigned k = __float_as_uint(norms[t * 64 + j]);
      int idx = t * 64 + j;
      if (k > T) { selkey[g] = k; selidx[g] = idx; ++g; }
      else if (k == T) {
        if (e < need_eq) { selkey[total_gt + e] = k; selidx[total_gt + e] = idx; }
        ++e;
      }
    }
    __syncthreads();
    if (t < KPROM) {  // stable rank: value desc, index asc == lax.top_k
      unsigned mk = selkey[t];
      int mi = selidx[t];
      int rank = 0;
      for (int q2 = 0; q2 < KPROM; ++q2) {
        unsigned qk = selkey[q2];
        int qi = selidx[q2];
        rank += (qk > mk || (qk == mk && qi < mi)) ? 1 : 0;
      }
      topidx[rank] = mi;
    }
    flag_set(wsb + F_TOPK);
  } else if (bid == 1) {
    // ---- lmean ----
    f32x4 a = {0.f, 0.f, 0.f, 0.f};
    for (int p = 0; p < 128; ++p) a += ((const f32x4*)lpart)[p * 256 + t];
    ((f32x4*)lmean)[t] = a * (1.f / 8192.f);
    flag_set(wsb + F_LMEAN);
  } else if (bid < 18) {
    // ---- q = wq @ lmean + bq : 64 dims/block ----
    flag_wait(wsb + F_LMEAN, 1);
    int d0 = (bid - 2) * 64;
    for (int ii = 0; ii < 16; ++ii) {
      int d = d0 + ii * 4 + w;
      const f32x4* row = (const f32x4*)(wq + (size_t)d * DIMV);
      const f32x4* lm = (const f32x4*)lmean;
      float s = 0.f;
#pragma unroll
      for (int c = 0; c < 4; ++c) {
        f32x4 a = row[c * 64 + lane], bb = lm[c * 64 + lane];
        s += a.x * bb.x + a.y * bb.y + a.z * bb.z + a.w * bb.w;
      }
      s = wave_sum(s);
      if (lane == 0) qv[d] = s + bq[d];
    }
    flag_set(wsb + F_Q);
  } else if (bid < 34) {
    // ---- rv += q[d] * wk[d][:] : 64 d's/block, atomic combine ----
    flag_wait(wsb + F_Q, 16);
    int d0 = (bid - 18) * 64;
    f32x4 a = {0.f, 0.f, 0.f, 0.f};
    for (int dd = 0; dd < 64; ++dd) {
      float qd = qv[d0 + dd];
      f32x4 v = ((const f32x4*)(wk + (size_t)(d0 + dd) * DIMV))[t];
      a += v * qd;
    }
    atomicAdd(&rv[t * 4 + 0], a.x);
    atomicAdd(&rv[t * 4 + 1], a.y);
    atomicAdd(&rv[t * 4 + 2], a.z);
    atomicAdd(&rv[t * 4 + 3], a.w);
    flag_set(wsb + F_RV);
  } else if (bid < 42) {
    // ---- write_s + logits: 64 rows/block (bk.q shift & softmax scale argmax-invariant) ----
    flag_wait(wsb + F_RV, 16);
    flag_wait(wsb + F_TOPK, 1);
    int sp = s_ptr[0];
    int r0 = (bid - 34) * 64;
    const f32x4* rvv = (const f32x4*)rv;
    for (int ii = 0; ii < 16; ++ii) {
      int r = r0 + ii * 4 + w;
      int k = (r - sp + SSZ) & (SSZ - 1);
      const f32x4* src = (const f32x4*)((k < KPROM) ? (cand + (size_t)topidx[k] * DIMV)
                                                    : (s_memory + (size_t)r * DIMV));
      f32x4* dst = (f32x4*)(out_s + (size_t)r * DIMV);
      float s = 0.f;
#pragma unroll
      for (int c = 0; c < 4; ++c) {
        int i = c * 64 + lane;
        f32x4 x = src[i], y = rvv[i];
        dst[i] = x;
        s += x.x * y.x + x.y * y.y + x.z * y.z + x.w * y.w;
      }
      s = wave_sum(s);
      if (lane == 0) logits[r] = s;
    }
    if (bid == 34 && t == 0) out_sptr[0] = (float)((sp + KPROM) % SSZ);
    flag_set(wsb + F_WS);
  } else if (bid == 42) {
    // ---- best = argmax(logits); cnorm ----
    flag_wait(wsb + F_WS, 8);
    float v0 = logits[t], v1 = logits[t + 256];
    float bv;
    int bidx;
    if (v1 > v0) { bv = v1; bidx = t + 256; } else { bv = v0; bidx = t; }
    wave_maxidx(bv, bidx);
    if (lane == 0) { swv[w] = bv; swi[w] = bidx; }
    __syncthreads();
    if (t == 0) {
      float a = swv[0]; int ai = swi[0];
      for (int i = 1; i < 4; ++i)
        if (swv[i] > a || (swv[i] == a && swi[i] < ai)) { a = swv[i]; ai = swi[i]; }
      bestp[0] = ai;
    }
    __syncthreads();
    int bi = bestp[0];
    f32x4 c4 = ((const f32x4*)(out_s + (size_t)bi * DIMV))[t];
    float s = c4.x * c4.x + c4.y * c4.y + c4.z * c4.z + c4.w * c4.w;
    s = wave_sum(s);
    __syncthreads();
    if (lane == 0) swv[w] = s;
    __syncthreads();
    if (t == 0) cnormp[0] = sqrtf(swv[0] + swv[1] + swv[2] + swv[3]);
    flag_set(wsb + F_BEST);
  } else if (bid < 59) {
    // ---- sims vs candidate: 256 rows/block, fp32 ----
    flag_wait(wsb + F_BEST, 1);
    int base = (bid - 43) * 256;
    const f32x4* cp = (const f32x4*)(out_s + (size_t)bestp[0] * DIMV);
    float cn = fmaxf(cnormp[0], 1e-12f);
    for (int ii = 0; ii < 64; ++ii) {
      int row = base + ii * 4 + w;
      const f32x4* mp = (const f32x4*)(m + (size_t)row * DIMV);
      float sd = 0.f;
#pragma unroll
      for (int c = 0; c < 4; ++c) {
        int i = c * 64 + lane;
        f32x4 v = mp[i], u = cp[i];
        sd += v.x * u.x + v.y * u.y + v.z * u.z + v.w * u.w;
      }
      sd = wave_sum(sd);
      if (lane == 0) sims[row] = sd / (fmaxf(mnorm[row], 1e-12f) * cn);
    }
    flag_set(wsb + F_SIMS);
  } else if (bid == 59) {
    // ---- decide + out_mu + out_lu + ctl export ----
    flag_wait(wsb + F_SIMS, 16);
    flag_wait(wsb + F_PAIR, NTILE);
    // A: internal pairwise max
    float bv = -3.402823466e38f;
    int bidx = 0x7FFFFFFF;
    for (int i = t; i < NTILE; i += 256) {
      float v = pv[i];
      int fi = pidx[i];
      if (v > bv || (v == bv && fi < bidx)) { bv = v; bidx = fi; }
    }
    wave_maxidx(bv, bidx);
    if (lane == 0) { swv[w] = bv; swi[w] = bidx; }
    __syncthreads();
    if (t == 0) {
      float a = swv[0]; int ai = swi[0];
      for (int i = 1; i < 4; ++i)
        if (swv[i] > a || (swv[i] == a && swi[i] < ai)) { a = swv[i]; ai = swi[i]; }
      s_f[0] = a; s_i[0] = ai;
    }
    __syncthreads();
    // B: argmax(sims), first occurrence
    bv = -3.402823466e38f;
    bidx = 0x7FFFFFFF;
#pragma unroll
    for (int j = 0; j < 16; ++j) {
      int i = t * 16 + j;
      float v = sims[i];
      if (v > bv) { bv = v; bidx = i; }
    }
    wave_maxidx(bv, bidx);
    if (lane == 0) { swv[w] = bv; swi[w] = bidx; }
    __syncthreads();
    if (t == 0) {
      float a = swv[0]; int ai = swi[0];
      for (int i = 1; i < 4; ++i)
        if (swv[i] > a || (swv[i] == a && swi[i] < ai)) { a = swv[i]; ai = swi[i]; }
      s_f[1] = a; s_i[1] = ai;
    }
    __syncthreads();
    // C: mu stats
    float muv[16];
    float sum = 0.f, mnv = 3.402823466e38f;
    int mni = 0x7FFFFFFF, zf = 0;
#pragma unroll
    for (int j = 0; j < 16; ++j) {
      int i = t * 16 + j;
      float v = mu[i];
      muv[j] = v;
      sum += v;
      if (v < mnv) { mnv = v; mni = i; }
      if (v == 0.f) zf = 1;
    }
    sum = wave_sum(sum);
    wave_minidx(mnv, mni);
#pragma unroll
    for (int o = 32; o > 0; o >>= 1) zf |= __shfl_down(zf, o, 64);
    if (lane == 0) { ssum[w] = sum; swv[w] = mnv; swi[w] = mni; szf[w] = zf; }
    __syncthreads();
    if (t == 0) {
      float muSum = 0.f;
      int anyz = 0;
      float a = swv[0]; int li = swi[0];
      for (int i = 0; i < 4; ++i) {
        muSum += ssum[i];
        anyz |= szf[i];
        if (i > 0 && (swv[i] < a || (swv[i] == a && swi[i] < li))) { a = swv[i]; li = swi[i]; }
      }
      float muMean = muSum / 4096.f;
      float internal_sim = s_f[0];
      int iflat = s_i[0];
      float sim_cand = s_f[1];
      int msi = s_i[1];
      int branch, i1 = -1, i2 = -1;
      float u1 = 0.f, u2 = 0.f;
      if (anyz) {
        branch = 0; i1 = li; u1 = muMean + 1e-5f;
      } else if (sim_cand > 0.98f) {
        branch = 1; i1 = msi; u1 = (mu[msi] + muMean) * 0.5f;
      } else if (internal_sim > 0.98f) {
        branch = 2; i1 = iflat / MSZ; i2 = iflat - (iflat / MSZ) * MSZ;
        float o1 = mu[i1], o2 = mu[i2];
        u1 = (o1 + o2) * 0.5f;
        u2 = (muSum - o1 + u1) / 4096.f + 1e-5f;  // mean recomputed after idx1 write
      } else {
        if (cnormp[0] > mnorm[li]) { branch = 0; i1 = li; u1 = muMean + 1e-5f; }
        else branch = 4;
      }
      s_i[2] = branch; s_i[3] = i1; s_i[4] = i2;
      s_f[2] = u1; s_f[3] = u2;
      wsb[2] = branch; wsb[3] = i1; wsb[4] = i2; wsb[5] = bestp[0];
    }
    __syncthreads();
    // D: out_mu + argmax of updated mu
    int branch = s_i[2], i1 = s_i[3], i2v = s_i[4];
    float u1 = s_f[2], u2 = s_f[3];
    bv = -3.402823466e38f;
    bidx = 0x7FFFFFFF;
#pragma unroll
    for (int j = 0; j < 16; ++j) {
      int i = t * 16 + j;
      float v = muv[j];
      if (branch != 4 && i == i1) v = u1;
      if (branch == 2 && i == i2v) v = u2;
      out_mu[i] = v;
      if (v > bv) { bv = v; bidx = i; }
    }
    wave_maxidx(bv, bidx);
    __syncthreads();
    if (lane == 0) { swv[w] = bv; swi[w] = bidx; }
    __syncthreads();
    if (t == 0) {
      float a = swv[0]; int ai = swi[0];
      for (int i = 1; i < 4; ++i)
        if (swv[i] > a || (swv[i] == a && swi[i] < ai)) { a = swv[i]; ai = swi[i]; }
      wsb[1] = ai;  // mi
    }
    // E: ltier — lj = argmin(lu), mean(lu) pre-write
    float luv[32];
    sum = 0.f; mnv = 3.402823466e38f; mni = 0x7FFFFFFF;
#pragma unroll
    for (int j = 0; j < 32; ++j) {
      int i = t * 32 + j;
      float v = lu[i];
      luv[j] = v;
      sum += v;
      if (v < mnv) { mnv = v; mni = i; }
    }
    sum = wave_sum(sum);
    wave_minidx(mnv, mni);
    __syncthreads();
    if (lane == 0) { swv[w] = mnv; swi[w] = mni; ssum[w] = sum; }
    __syncthreads();
    if (t == 0) {
      float a = swv[0]; int ai = swi[0];
      float ls = 0.f;
      for (int i = 0; i < 4; ++i) {
        ls += ssum[i];
        if (i > 0 && (swv[i] < a || (swv[i] == a && swi[i] < ai))) { a = swv[i]; ai = swi[i]; }
      }
      s_i[5] = ai;
      s_f[4] = ls / 8192.f;
      wsb[0] = ai;  // lj
    }
    __syncthreads();
    int lj = s_i[5];
    float lmv = s_f[4];
#pragma unroll
    for (int j = 0; j < 32; ++j) {
      int i = t * 32 + j;
      out_lu[i] = (i == lj) ? lmv : luv[j];
    }
  } else if (bid >= 64 && bid < 64 + NTILE) {
    // ---- pairmax: one 128x128 bf16-MFMA tile per block (proven round-1 structure) ----
    int b = bid - 64;
    int bi = 0, acc0 = 0;
    while (acc0 + bi + 1 <= b) { acc0 += bi + 1; ++bi; }
    int bj = b - acc0;
    int wr = w >> 1, wc = w & 1;
    int rl = lane & 15, kq = (lane >> 4) * 8, riq = (lane >> 4) * 4;
    int rowA0 = bi * 128, rowB0 = bj * 128;

    f32x4 acc[4][4];
    f32x4 z = {0.f, 0.f, 0.f, 0.f};
#pragma unroll
    for (int i = 0; i < 4; ++i)
#pragma unroll
      for (int j = 0; j < 4; ++j) acc[i][j] = z;

    for (int kc = 0; kc < DIMV; kc += 64) {
      __syncthreads();
#pragma unroll
      for (int c = 0; c < 4; ++c) {
        int chunk = c * 256 + t;
        int r = chunk >> 3, co = (chunk & 7) * 8;
        u32x4 va = *(const u32x4*)(mb + (size_t)(rowA0 + r) * DIMV + kc + co);
        u32x4 vb = *(const u32x4*)(mb + (size_t)(rowB0 + r) * DIMV + kc + co);
        *(u32x4*)(At + r * 72 + co) = va;
        *(u32x4*)(Bt + r * 72 + co) = vb;
      }
      __syncthreads();
#pragma unroll
      for (int ks = 0; ks < 64; ks += 32) {
        bf16x8 af[4], bfv[4];
#pragma unroll
        for (int ti = 0; ti < 4; ++ti)
          af[ti] = *(const bf16x8*)(At + (wr * 64 + ti * 16 + rl) * 72 + ks + kq);
#pragma unroll
        for (int tj = 0; tj < 4; ++tj)
          bfv[tj] = *(const bf16x8*)(Bt + (wc * 64 + tj * 16 + rl) * 72 + ks + kq);
#pragma unroll
        for (int ti = 0; ti < 4; ++ti)
#pragma unroll
          for (int tj = 0; tj < 4; ++tj)
            acc[ti][tj] = __builtin_amdgcn_mfma_f32_16x16x32_bf16(af[ti], bfv[tj], acc[ti][tj], 0, 0, 0);
      }
    }
    float ni[16], nj[4];
#pragma unroll
    for (int ti = 0; ti < 4; ++ti)
#pragma unroll
      for (int r = 0; r < 4; ++r)
        ni[ti * 4 + r] = fmaxf(mnorm[rowA0 + wr * 64 + ti * 16 + riq + r], 1e-12f);
#pragma unroll
    for (int tj = 0; tj < 4; ++tj)
      nj[tj] = fmaxf(mnorm[rowB0 + wc * 64 + tj * 16 + rl], 1e-12f);

    float bv = -3.402823466e38f;
    int bidx = 0x7FFFFFFF;
#pragma unroll
    for (int ti = 0; ti < 4; ++ti)
#pragma unroll
      for (int tj = 0; tj < 4; ++tj)
#pragma unroll
        for (int r = 0; r < 4; ++r) {
          int gi = rowA0 + wr * 64 + ti * 16 + riq + r;  // C/D row = quad*4+reg
          int gj = rowB0 + wc * 64 + tj * 16 + rl;       // C/D col = lane&15
          if (gi > gj) {
            float s = acc[ti][tj][r] / (ni[ti * 4 + r] * nj[tj]);
            int fi = gi * MSZ + gj;
            if (s > bv || (s == bv && fi < bidx)) { bv = s; bidx = fi; }
          }
        }
    wave_maxidx(bv, bidx);
    if (lane == 0) { swv[w] = bv; swi[w] = bidx; }
    __syncthreads();
    if (t == 0) {
      float a = swv[0]; int ai = swi[0];
      for (int i = 1; i < 4; ++i)
        if (swv[i] > a || (swv[i] == a && swi[i] < ai)) { a = swv[i]; ai = swi[i]; }
      pv[b] = a;
      pidx[b] = ai;
    }
    flag_set(wsb + F_PAIR);
  }
  // blocks 60..63 and 592..767: straight to barrier

  gridbar(wsb + 10, wsb + 11);

  // ================= final: out_m + out_l (scratch region now dead) =================
  int lj = wsb[0], miX = wsb[1], branch = wsb[2], i1 = wsb[3], i2 = wsb[4], bestI = wsb[5];
  for (int v = bid; v < 12288; v += NBLK) {
    if (v < 4096) {
      int row = v;
      int mode = 0;
      if ((branch == 0 && row == i1) || (branch == 2 && row == i2)) mode = 1;
      else if (branch == 1 && row == i1) mode = 2;
      else if (branch == 2 && row == i1) mode = 3;
      f32x4* dst = (f32x4*)(out_m + (size_t)row * DIMV);
      if (mode == 0) {
        dst[t] = ((const f32x4*)(m + (size_t)row * DIMV))[t];
      } else if (mode == 1) {
        dst[t] = ((const f32x4*)(out_s + (size_t)bestI * DIMV))[t];
      } else {
        f32x4 a = ((const f32x4*)(m + (size_t)row * DIMV))[t];
        f32x4 bb = (mode == 2) ? ((const f32x4*)(out_s + (size_t)bestI * DIMV))[t]
                               : ((const f32x4*)(m + (size_t)i2 * DIMV))[t];
        f32x4 vv = (a + bb) * 0.5f;
        float ss = vv.x * vv.x + vv.y * vv.y + vv.z * vv.z + vv.w * vv.w;
        ss = wave_sum(ss);
        if (lane == 0) ssum[w] = ss;
        __syncthreads();
        float nrm = fmaxf(sqrtf(ssum[0] + ssum[1] + ssum[2] + ssum[3]), 1e-12f);
        dst[t] = vv / nrm;
        __syncthreads();
      }
    } else {
      int row = v - 4096;
      f32x4 vv = ((const f32x4*)(l_memory + (size_t)row * DIMV))[t];
      if (row == lj) {
        // recompute out_m[miX] inline (no cross-block dependency)
        int mode = 0;
        if ((branch == 0 && miX == i1) || (branch == 2 && miX == i2)) mode = 1;
        else if (branch == 1 && miX == i1) mode = 2;
        else if (branch == 2 && miX == i1) mode = 3;
        f32x4 mv;
        if (mode == 0) {
          mv = ((const f32x4*)(m + (size_t)miX * DIMV))[t];
        } else if (mode == 1) {
          mv = ((const f32x4*)(out_s + (size_t)bestI * DIMV))[t];
        } else {
          f32x4 a = ((const f32x4*)(m + (size_t)miX * DIMV))[t];
          f32x4 bb = (mode == 2) ? ((const f32x4*)(out_s + (size_t)bestI * DIMV))[t]
                                 : ((const f32x4*)(m + (size_t)i2 * DIMV))[t];
          f32x4 vm = (a + bb) * 0.5f;
          float ss = vm.x * vm.x + vm.y * vm.y + vm.z * vm.z + vm.w * vm.w;
          ss = wave_sum(ss);
          if (lane == 0) ssum[w] = ss;
          __syncthreads();
          float nrm = fmaxf(sqrtf(ssum[0] + ssum[1] + ssum[2] + ssum[3]), 1e-12f);
          mv = vm / nrm;
          __syncthreads();
        }
        vv = vv * 0.9f + mv * 0.1f;
      }
      ((f32x4*)(out_l + (size_t)row * DIMV))[t] = vv;
    }
  }
}

extern "C" void kernel_launch(void* const* d_in, const int* in_sizes, int n_in,
                              void* d_out, int out_size, void* d_ws, size_t ws_size,
                              hipStream_t stream) {
  (void)in_sizes; (void)n_in; (void)out_size; (void)ws_size;
  const float* cand = (const float*)d_in[0];
  const float* s_memory = (const float*)d_in[1];
  const float* m_memory = (const float*)d_in[2];
  const float* l_memory = (const float*)d_in[3];
  const float* m_utility = (const float*)d_in[4];
  const float* l_utility = (const float*)d_in[5];
  const float* wq = (const float*)d_in[6];
  const float* bq = (const float*)d_in[7];
  const float* wk = (const float*)d_in[8];
  // d_in[9] = bk: bk.q is a constant logit shift -> argmax-invariant, unused
  const int* s_ptr = (const int*)d_in[10];

  float* out = (float*)d_out;
  int* wsb = (int*)d_ws;

  hipMemsetAsync(d_ws, 0, 96, stream);  // ctl + barrier counters + flags

  void* args[] = {(void*)&cand, (void*)&s_memory, (void*)&m_memory, (void*)&l_memory,
                  (void*)&m_utility, (void*)&l_utility, (void*)&wq, (void*)&bq,
                  (void*)&wk, (void*)&s_ptr, (void*)&out, (void*)&wsb};
  hipError_t e = hipLaunchCooperativeKernel((const void*)kMega, dim3(NBLK), dim3(256),
                                            args, 0, stream);
  if (e != hipSuccess) {
    // fallback: plain launch — 768 blocks at 3/CU are co-resident on an otherwise-idle device
    kMega<<<NBLK, 256, 0, stream>>>(cand, s_memory, m_memory, l_memory, m_utility,
                                    l_utility, wq, bq, wk, s_ptr, out, wsb);
  }
}